// Round 7
// baseline (191.602 us; speedup 1.0000x reference)
//
#include <hip/hip_runtime.h>
#include <hip/hip_cooperative_groups.h>
#include <cstdint>
#include <cstddef>

namespace cg = cooperative_groups;

#define Bn 64
#define Sn 512
#define Hn 768
#define Tn 50
#define CH 32   // scan chunk length (steps)
#define NCH 16  // max chunks per sequence
#define EP 52   // padded row stride for exp(trans) tables
#define BK 64

typedef short short8 __attribute__((ext_vector_type(8)));
typedef float floatx4 __attribute__((ext_vector_type(4)));

__device__ __forceinline__ uint32_t rne_bf16(float x) {
  uint32_t u = __float_as_uint(x);
  return (u + 0x7FFFu + ((u >> 16) & 1u)) >> 16;
}
__device__ __forceinline__ uint32_t pack2(float a, float b) {
  return rne_bf16(a) | (rne_bf16(b) << 16);
}
__device__ __forceinline__ float rdlane(float v, int i) {
  return __uint_as_float(__builtin_amdgcn_readlane(__float_as_uint(v), i));
}

// Single cooperative kernel: P0 prep | P1 emissions (MFMA) | P2 chunked
// scans | P3 stitch, separated by grid.sync(). 512 virtual blocks x 256;
// grid-stride loops tolerate a clamped grid. launch_bounds(256,2): VGPR
// cap 256 (e[50] stays in regs; 2 blocks/CU co-resident).
__global__ __launch_bounds__(256, 2) void fused_kernel(
    const float* __restrict__ hidden, const float* __restrict__ W,
    const float* __restrict__ bias, const float* __restrict__ startT,
    const float* __restrict__ endT, const float* __restrict__ trans,
    const int* __restrict__ tag, const int* __restrict__ mask,
    float* __restrict__ em, uint32_t* __restrict__ wfrag,
    int* __restrict__ lenbuf, float* __restrict__ Ee, float* __restrict__ EeT,
    float* __restrict__ fvec, float* __restrict__ gvec, float* __restrict__ Lf,
    float* __restrict__ numpart, float* __restrict__ out) {
  cg::grid_group grid = cg::this_grid();
  const int tid = threadIdx.x;
  const int nblk = gridDim.x;
  __shared__ char lds_raw[64 * 128];

  // ---------------- P0: lengths, W-fragment pack, exp(trans) tables --------
  for (int task = blockIdx.x; task < 89; task += nblk) {
    if (task < 64) {
      if (tid < 64) {
        int s = 0;
        for (int t = tid; t < Sn; t += 64) s += mask[task * Sn + t];
#pragma unroll
        for (int off = 1; off < 64; off <<= 1) s += __shfl_xor(s, off);
        if (tid == 0) lenbuf[task] = s;
      }
    } else if (task < 88) {
      const int gid = (task - 64) * 256 + tid;  // [0, 6144)
      const int f = gid >> 6;
      const int l = gid & 63;
      const int ks = f >> 2, nt = f & 3;
      const int col = nt * 16 + (l & 15);
      const int k0 = ks * 32 + (l >> 4) * 8;
      float v[8];
#pragma unroll
      for (int j = 0; j < 8; ++j)
        v[j] = (col < Tn) ? W[(size_t)(k0 + j) * Tn + col] : 0.f;
      uint4 d;
      d.x = pack2(v[0], v[1]);
      d.y = pack2(v[2], v[3]);
      d.z = pack2(v[4], v[5]);
      d.w = pack2(v[6], v[7]);
      ((uint4*)wfrag)[gid] = d;
    } else {
      for (int gid = tid; gid < Tn * Tn; gid += 256) {
        const int r = gid / Tn, cl = gid - r * Tn;
        const float v = __expf(trans[gid]);
        Ee[r * EP + cl] = v;
        EeT[cl * EP + r] = v;
      }
    }
  }
  grid.sync();

  // ---------------- P1: emissions via MFMA ----------------
  for (int eb = blockIdx.x; eb < Bn * 8; eb += nblk) {
    const int bb = eb >> 3, cc = eb & 7;
    if (mask[bb * Sn + cc * 64] == 0) continue;  // prefix mask: rows >= len
    const int lane = tid & 63;
    const int w = tid >> 6;
    const int g = lane >> 4;
    const int li = lane & 15;
    const int row0 = eb * 64;

    floatx4 acc[4];
#pragma unroll
    for (int nt = 0; nt < 4; ++nt) acc[nt] = (floatx4)0.f;

    const float* hbase = hidden + (size_t)row0 * Hn;
    const short8* wf = (const short8*)wfrag;

#define LOADCH(dst, ch)                                                      \
  _Pragma("unroll") for (int k = 0; k < 4; ++k) dst[k] =                     \
      *(const float4*)(hbase + (size_t)(w * 16 + 4 * k + g) * Hn + (ch)*BK + \
                       li * 4);
#define WRITELDS(src)                                                        \
  _Pragma("unroll") for (int k = 0; k < 4; ++k) {                            \
    const int r = w * 16 + 4 * k + g;                                        \
    const uint32_t b0 = pack2(src[k].x, src[k].y);                           \
    const uint32_t b1 = pack2(src[k].z, src[k].w);                           \
    const int byteoff = r * 128 + ((li * 8) ^ ((r & 7) << 4));               \
    *(uint2*)(lds_raw + byteoff) = make_uint2(b0, b1);                       \
  }
#define COMPUTE(ch)                                                          \
  _Pragma("unroll") for (int ks = 0; ks < 2; ++ks) {                         \
    const int r = w * 16 + li;                                               \
    const int kb = ks * 64 + g * 16;                                         \
    const short8 af =                                                        \
        *(const short8*)(lds_raw + r * 128 + (kb ^ ((r & 7) << 4)));         \
    const int ksg = (ch)*2 + ks;                                             \
    _Pragma("unroll") for (int nt = 0; nt < 4; ++nt) {                       \
      const short8 bf = wf[(ksg * 4 + nt) * 64 + lane];                      \
      acc[nt] =                                                              \
          __builtin_amdgcn_mfma_f32_16x16x32_bf16(af, bf, acc[nt], 0, 0, 0); \
    }                                                                        \
  }

    float4 pfA[4], pfB[4];
    LOADCH(pfA, 0)
    LOADCH(pfB, 1)
#pragma unroll
    for (int chp = 0; chp < Hn / BK / 2; ++chp) {
      const int ch = 2 * chp;
      WRITELDS(pfA)
      if (ch + 2 < Hn / BK) LOADCH(pfA, ch + 2)
      COMPUTE(ch)
      WRITELDS(pfB)
      if (ch + 3 < Hn / BK) LOADCH(pfB, ch + 3)
      COMPUTE(ch + 1)
    }
#undef LOADCH
#undef WRITELDS
#undef COMPUTE

#pragma unroll
    for (int nt = 0; nt < 4; ++nt) {
      const int col = nt * 16 + li;
      if (col < Tn) {
        const float bs = bias[col];
#pragma unroll
        for (int r = 0; r < 4; ++r) {
          const int row = row0 + w * 16 + g * 4 + r;
          em[(size_t)row * Tn + col] = acc[nt][r] + bs;
        }
      }
    }
  }
  grid.sync();

  // ---------------- P2: chunked scans (wave = one task) ----------------
  for (int tb = blockIdx.x; tb < Bn * 8; tb += nblk) {
    const int task = tb * 4 + (tid >> 6);  // [0, 2048)
    const int lane = tid & 63;
    const int b = task >> 5;
    const int c = (task >> 1) & (NCH - 1);
    const int dir = task & 1;
    const int len = lenbuf[b];
    const int t0 = 1 + c * CH;
    if (t0 >= len || (dir && c == 0)) continue;
    const int t1 = (t0 + CH < len) ? t0 + CH : len;
    const int L = t1 - t0;
    const int jc = lane < Tn ? lane : 0;
    const bool live = lane < Tn;
    const float* emb = em + (size_t)b * Sn * Tn;

    if (!dir) {  // chunk numerator partial; lane = timestep
      float npv = 0.f;
      if (lane < L) {
        const int t = t0 + lane;
        const int tp = tag[b * Sn + t - 1], tc = tag[b * Sn + t];
        npv = trans[tp * Tn + tc] + emb[(size_t)t * Tn + tc];
      }
#pragma unroll
      for (int off = 1; off < 64; off <<= 1) npv += __shfl_xor(npv, off);
      if (lane == 0) numpart[b * NCH + c] = npv;
    }

    const float* ebase = (dir ? Ee : EeT) + jc * EP;
    float e[Tn];
#pragma unroll
    for (int i = 0; i < Tn; ++i) e[i] = ebase[i];

    float Cacc = 0.f;
    float q;
    if (!dir)
      q = live ? (c == 0 ? __expf(startT[jc] + emb[jc]) : 1.f) : 0.f;
    else
      q = live ? 1.f : 0.f;

#define T_OF(k) (dir ? (t1 - 1 - (k)) : (t0 + (k)))
    float ld1 = emb[(size_t)T_OF(0) * Tn + jc];
    const float ld2 = emb[(size_t)T_OF(L > 1 ? 1 : 0) * Tn + jc];
    float ee = live ? __expf(ld1) : 0.f;
    ld1 = ld2;

    for (int k = 0; k < L; ++k) {
      const float ee_cur = ee;
      const int kn = (k + 2 < L) ? k + 2 : L - 1;
      const float ldn = emb[(size_t)T_OF(kn) * Tn + jc];
      ee = live ? __expf(ld1) : 0.f;
      ld1 = ldn;

      const float x = dir ? ee_cur * q : q;
      float s0 = 0.f, s1 = 0.f, s2 = 0.f, s3 = 0.f;
#pragma unroll
      for (int i = 0; i < 48; i += 4) {
        s0 = fmaf(rdlane(x, i + 0), e[i + 0], s0);
        s1 = fmaf(rdlane(x, i + 1), e[i + 1], s1);
        s2 = fmaf(rdlane(x, i + 2), e[i + 2], s2);
        s3 = fmaf(rdlane(x, i + 3), e[i + 3], s3);
      }
      s0 = fmaf(rdlane(x, 48), e[48], s0);
      s1 = fmaf(rdlane(x, 49), e[49], s1);
      const float s = (s0 + s1) + (s2 + s3);
      q = dir ? s : ee_cur * s;

      if ((k & 7) == 7) {
        float M = q;
#pragma unroll
        for (int off = 1; off < 64; off <<= 1) M = fmaxf(M, __shfl_xor(M, off));
        const float r = __builtin_amdgcn_rcpf(M);
        q *= r;
        Cacc -= __logf(r);
      }
    }
#undef T_OF

    float M = q;
#pragma unroll
    for (int off = 1; off < 64; off <<= 1) M = fmaxf(M, __shfl_xor(M, off));
    const float r = __builtin_amdgcn_rcpf(M);
    const float qn = live ? q * r : 0.f;
    Cacc -= __logf(r);
    if (dir) {
      gvec[((size_t)b * NCH + c) * 64 + lane] = qn;
    } else {
      fvec[((size_t)b * NCH + c) * 64 + lane] = qn;
      if (lane == 0) Lf[b * NCH + c] = Cacc;
    }
  }
  grid.sync();

  // ---------------- P3: stitch ----------------
  for (int b = blockIdx.x; b < Bn; b += nblk) {
    if (tid >= 64) continue;
    const int lane = tid;
    const int len = lenbuf[b];
    const int C = (len - 1 + CH - 1) / CH;
    const int jc = lane < Tn ? lane : 0;
    const bool live = lane < Tn;
    const float* emb = em + (size_t)b * Sn * Tn;

    float np = (lane < C) ? numpart[b * NCH + lane] : 0.f;
#pragma unroll
    for (int off = 1; off < 64; off <<= 1) np += __shfl_xor(np, off);
    const int tg0 = tag[b * Sn];
    const int tgl = tag[b * Sn + len - 1];
    np += startT[tg0] + emb[tg0] + endT[tgl];

    float den;
    if (C == 0) {  // len == 1
      float v = live ? (startT[jc] + emb[jc] + endT[jc]) : -INFINITY;
      float M = v;
#pragma unroll
      for (int off = 1; off < 64; off <<= 1) M = fmaxf(M, __shfl_xor(M, off));
      float s = __expf(v - M);
#pragma unroll
      for (int off = 1; off < 64; off <<= 1) s += __shfl_xor(s, off);
      den = M + __logf(s);
    } else {
      const float ev = live ? __expf(endT[jc]) : 0.f;
      float d = fvec[((size_t)b * NCH + C - 1) * 64 + lane] * ev;
#pragma unroll
      for (int off = 1; off < 64; off <<= 1) d += __shfl_xor(d, off);
      den = Lf[b * NCH + C - 1] + __logf(d);
      for (int c2 = 1; c2 < C; ++c2) {
        const float g = gvec[((size_t)b * NCH + c2) * 64 + lane];
        const float f = fvec[((size_t)b * NCH + c2 - 1) * 64 + lane];
        float dot = g * f;
        float gs = g;
#pragma unroll
        for (int off = 1; off < 64; off <<= 1) {
          dot += __shfl_xor(dot, off);
          gs += __shfl_xor(gs, off);
        }
        den += Lf[b * NCH + c2 - 1] + __logf(dot) - __logf(gs);
      }
    }
    if (lane == 0) out[b] = den - np;
  }
}

extern "C" void kernel_launch(void* const* d_in, const int* in_sizes, int n_in,
                              void* d_out, int out_size, void* d_ws,
                              size_t ws_size, hipStream_t stream) {
  const float* hidden = (const float*)d_in[0];
  const float* W = (const float*)d_in[1];
  const float* bias = (const float*)d_in[2];
  const float* startT = (const float*)d_in[3];
  const float* endT = (const float*)d_in[4];
  const float* trans = (const float*)d_in[5];
  const int* tag = (const int*)d_in[6];
  const int* mask = (const int*)d_in[7];
  float* out = (float*)d_out;

  char* ws = (char*)d_ws;
  float* em = (float*)ws;                       // 6,553,600 B
  uint32_t* wfrag = (uint32_t*)(ws + 6553600);  //    98,304 B
  int* lenbuf = (int*)(ws + 6651904);           //       256 B
  float* Ee = (float*)(ws + 6652160);           //    10,816 B
  float* EeT = (float*)(ws + 6662976);          //    10,816 B
  float* fvec = (float*)(ws + 6673792);         //   262,144 B
  float* gvec = (float*)(ws + 6935936);         //   262,144 B
  float* Lf = (float*)(ws + 7198080);           //     4,096 B
  float* numpart = (float*)(ws + 7202176);      //     4,096 B

  int nb = 0;
  hipOccupancyMaxActiveBlocksPerMultiprocessor(&nb, fused_kernel, 256, 0);
  if (nb < 1) nb = 1;
  int grid = nb * 256;  // 256 CUs on MI355X
  if (grid > 512) grid = 512;

  void* args[] = {(void*)&hidden, (void*)&W,      (void*)&bias,
                  (void*)&startT, (void*)&endT,   (void*)&trans,
                  (void*)&tag,    (void*)&mask,   (void*)&em,
                  (void*)&wfrag,  (void*)&lenbuf, (void*)&Ee,
                  (void*)&EeT,    (void*)&fvec,   (void*)&gvec,
                  (void*)&Lf,     (void*)&numpart, (void*)&out};
  hipLaunchCooperativeKernel((void*)fused_kernel, dim3(grid), dim3(256), args,
                             0, stream);
}

// Round 8
// 100.286 us; speedup vs baseline: 1.9106x; 1.9106x over previous
//
#include <hip/hip_runtime.h>
#include <cstdint>
#include <cstddef>

#define Bn 64
#define Sn 512
#define Hn 768
#define Tn 50
#define CH 32   // scan chunk length (steps)
#define NCH 16  // max chunks per sequence
#define EP 52   // padded row stride for exp(trans) tables
#define BK 64

typedef short short8 __attribute__((ext_vector_type(8)));
typedef float floatx4 __attribute__((ext_vector_type(4)));

__device__ __forceinline__ uint32_t rne_bf16(float x) {
  uint32_t u = __float_as_uint(x);
  return (u + 0x7FFFu + ((u >> 16) & 1u)) >> 16;
}
__device__ __forceinline__ uint32_t pack2(float a, float b) {
  return rne_bf16(a) | (rne_bf16(b) << 16);
}
__device__ __forceinline__ float rdlane(float v, int i) {
  return __uint_as_float(__builtin_amdgcn_readlane(__float_as_uint(v), i));
}

// ------ Kernel 0: prep — lengths + W fragment pack + exp(trans) + counters --
__global__ __launch_bounds__(256) void prep_kernel(
    const float* __restrict__ W, const float* __restrict__ trans,
    const int* __restrict__ mask, uint32_t* __restrict__ wfrag,
    int* __restrict__ lenbuf, float* __restrict__ Ee, float* __restrict__ EeT,
    int* __restrict__ counters) {
  const int blk = blockIdx.x;
  const int tid = threadIdx.x;
  if (blk < 64) {
    if (tid < 64) {
      int s = 0;
      for (int t = tid; t < Sn; t += 64) s += mask[blk * Sn + t];
#pragma unroll
      for (int off = 1; off < 64; off <<= 1) s += __shfl_xor(s, off);
      if (tid == 0) lenbuf[blk] = s;
    }
    return;
  }
  if (blk == 88) {  // exp(trans) tables + zero arrival counters
    if (tid < 64) counters[tid] = 0;
    for (int gid = tid; gid < Tn * Tn; gid += 256) {
      const int r = gid / Tn, cl = gid - r * Tn;
      const float v = __expf(trans[gid]);
      Ee[r * EP + cl] = v;
      EeT[cl * EP + r] = v;
    }
    return;
  }
  const int gid = (blk - 64) * 256 + tid;  // [0, 6144)
  const int f = gid >> 6;                  // 0..95
  const int l = gid & 63;
  const int ks = f >> 2, nt = f & 3;
  const int col = nt * 16 + (l & 15);
  const int k0 = ks * 32 + (l >> 4) * 8;
  float v[8];
#pragma unroll
  for (int j = 0; j < 8; ++j)
    v[j] = (col < Tn) ? W[(size_t)(k0 + j) * Tn + col] : 0.f;
  uint4 d;
  d.x = pack2(v[0], v[1]);
  d.y = pack2(v[2], v[3]);
  d.z = pack2(v[4], v[5]);
  d.w = pack2(v[6], v[7]);
  ((uint4*)wfrag)[gid] = d;
}

// ------ Kernel 1: emissions via MFMA, 2-deep ping-pong prefetch ------
// launch_bounds(256,2): VGPR cap 128 (r7 ran this body at 128, no spill)
// -> 2 blocks/CU co-resident -> 2x outstanding HBM loads.
__global__ __launch_bounds__(256, 2) void emissions_kernel(
    const float* __restrict__ hidden, const uint32_t* __restrict__ wfrag,
    const float* __restrict__ bias, const int* __restrict__ lenbuf,
    float* __restrict__ em) {
  const int blk = blockIdx.x;
  const int bb = blk >> 3, cc = blk & 7;
  if (cc * 64 >= lenbuf[bb]) return;  // rows never read by CRF
  const int tid = threadIdx.x;
  const int lane = tid & 63;
  const int w = tid >> 6;
  const int g = lane >> 4;
  const int li = lane & 15;
  const int row0 = blk * 64;
  __shared__ char lds_raw[64 * 128];

  floatx4 acc[4];
#pragma unroll
  for (int nt = 0; nt < 4; ++nt) acc[nt] = (floatx4)0.f;

  const float* hbase = hidden + (size_t)row0 * Hn;
  const short8* wf = (const short8*)wfrag;

#define LOADCH(dst, ch)                                                      \
  _Pragma("unroll") for (int k = 0; k < 4; ++k) dst[k] =                     \
      *(const float4*)(hbase + (size_t)(w * 16 + 4 * k + g) * Hn + (ch)*BK + \
                       li * 4);
#define WRITELDS(src)                                                        \
  _Pragma("unroll") for (int k = 0; k < 4; ++k) {                            \
    const int r = w * 16 + 4 * k + g;                                        \
    const uint32_t b0 = pack2(src[k].x, src[k].y);                           \
    const uint32_t b1 = pack2(src[k].z, src[k].w);                           \
    const int byteoff = r * 128 + ((li * 8) ^ ((r & 7) << 4));               \
    *(uint2*)(lds_raw + byteoff) = make_uint2(b0, b1);                       \
  }
#define COMPUTE(ch)                                                          \
  _Pragma("unroll") for (int ks = 0; ks < 2; ++ks) {                         \
    const int r = w * 16 + li;                                               \
    const int kb = ks * 64 + g * 16;                                         \
    const short8 af =                                                        \
        *(const short8*)(lds_raw + r * 128 + (kb ^ ((r & 7) << 4)));         \
    const int ksg = (ch)*2 + ks;                                             \
    _Pragma("unroll") for (int nt = 0; nt < 4; ++nt) {                       \
      const short8 bf = wf[(ksg * 4 + nt) * 64 + lane];                      \
      acc[nt] =                                                              \
          __builtin_amdgcn_mfma_f32_16x16x32_bf16(af, bf, acc[nt], 0, 0, 0); \
    }                                                                        \
  }

  float4 pfA[4], pfB[4];
  LOADCH(pfA, 0)
  LOADCH(pfB, 1)
#pragma unroll
  for (int chp = 0; chp < Hn / BK / 2; ++chp) {
    const int ch = 2 * chp;
    WRITELDS(pfA)
    if (ch + 2 < Hn / BK) LOADCH(pfA, ch + 2)
    COMPUTE(ch)
    WRITELDS(pfB)
    if (ch + 3 < Hn / BK) LOADCH(pfB, ch + 3)
    COMPUTE(ch + 1)
  }
#undef LOADCH
#undef WRITELDS
#undef COMPUTE

#pragma unroll
  for (int nt = 0; nt < 4; ++nt) {
    const int col = nt * 16 + li;
    if (col < Tn) {
      const float bs = bias[col];
#pragma unroll
      for (int r = 0; r < 4; ++r) {
        const int row = row0 + w * 16 + g * 4 + r;
        em[(size_t)row * Tn + col] = acc[nt][r] + bs;
      }
    }
  }
}

// ------ Kernel 2: chunked scans + last-arrival stitch ------
// Grid = Bn*NCH*2 single-wave blocks. All 32 blocks of a batch arrive at
// counters[b]; the 32nd runs the stitch. launch_bounds(64,1): VGPR cap 512
// so e[50] stays in registers.
__global__ __launch_bounds__(64, 1) void scan_stitch_kernel(
    const float* __restrict__ em, const float* __restrict__ startT,
    const float* __restrict__ endT, const float* __restrict__ trans,
    const float* __restrict__ Ee, const float* __restrict__ EeT,
    const int* __restrict__ tag, const int* __restrict__ lenbuf,
    float* __restrict__ fvec, float* __restrict__ gvec, float* __restrict__ Lf,
    float* __restrict__ numpart, int* __restrict__ counters,
    float* __restrict__ out) {
  const int blk = blockIdx.x;
  const int b = blk >> 5;
  const int c = (blk >> 1) & (NCH - 1);
  const int dir = blk & 1;  // 0 = forward (f), 1 = backward (g)
  const int len = lenbuf[b];
  const int t0 = 1 + c * CH;
  const int lane = threadIdx.x;
  const int jc = lane < Tn ? lane : 0;
  const bool live = lane < Tn;
  const float* emb = em + (size_t)b * Sn * Tn;
  const bool active = (t0 < len) && !(dir && c == 0);

  if (active) {
    const int t1 = (t0 + CH < len) ? t0 + CH : len;
    const int L = t1 - t0;

    if (!dir) {  // chunk numerator partial; lane = timestep
      float npv = 0.f;
      if (lane < L) {
        const int t = t0 + lane;
        const int tp = tag[b * Sn + t - 1], tc = tag[b * Sn + t];
        npv = trans[tp * Tn + tc] + emb[(size_t)t * Tn + tc];
      }
#pragma unroll
      for (int off = 1; off < 64; off <<= 1) npv += __shfl_xor(npv, off);
      if (lane == 0) numpart[b * NCH + c] = npv;
    }

    // e[i]: f needs E[i][jc] = EeT row jc; g needs E[jc][i] = Ee row jc.
    const float* ebase = (dir ? Ee : EeT) + jc * EP;
    float e[Tn];
#pragma unroll
    for (int i = 0; i < Tn; ++i) e[i] = ebase[i];

    float Cacc = 0.f;
    float q;
    if (!dir)
      q = live ? (c == 0 ? __expf(startT[jc] + emb[jc]) : 1.f) : 0.f;
    else
      q = live ? 1.f : 0.f;

#define T_OF(k) (dir ? (t1 - 1 - (k)) : (t0 + (k)))
    float ld1 = emb[(size_t)T_OF(0) * Tn + jc];
    const float ld2 = emb[(size_t)T_OF(L > 1 ? 1 : 0) * Tn + jc];
    float ee = live ? __expf(ld1) : 0.f;
    ld1 = ld2;

    for (int k = 0; k < L; ++k) {
      const float ee_cur = ee;
      const int kn = (k + 2 < L) ? k + 2 : L - 1;
      const float ldn = emb[(size_t)T_OF(kn) * Tn + jc];
      ee = live ? __expf(ld1) : 0.f;
      ld1 = ldn;

      const float x = dir ? ee_cur * q : q;  // g pre-multiplies by D_t
      float s0 = 0.f, s1 = 0.f, s2 = 0.f, s3 = 0.f;
#pragma unroll
      for (int i = 0; i < 48; i += 4) {
        s0 = fmaf(rdlane(x, i + 0), e[i + 0], s0);
        s1 = fmaf(rdlane(x, i + 1), e[i + 1], s1);
        s2 = fmaf(rdlane(x, i + 2), e[i + 2], s2);
        s3 = fmaf(rdlane(x, i + 3), e[i + 3], s3);
      }
      s0 = fmaf(rdlane(x, 48), e[48], s0);
      s1 = fmaf(rdlane(x, 49), e[49], s1);
      const float s = (s0 + s1) + (s2 + s3);
      q = dir ? s : ee_cur * s;  // f post-multiplies by D_t

      if ((k & 7) == 7) {
        float M = q;
#pragma unroll
        for (int off = 1; off < 64; off <<= 1) M = fmaxf(M, __shfl_xor(M, off));
        const float r = __builtin_amdgcn_rcpf(M);
        q *= r;
        Cacc -= __logf(r);
      }
    }
#undef T_OF

    float M = q;
#pragma unroll
    for (int off = 1; off < 64; off <<= 1) M = fmaxf(M, __shfl_xor(M, off));
    const float r = __builtin_amdgcn_rcpf(M);
    const float qn = live ? q * r : 0.f;
    Cacc -= __logf(r);
    if (dir) {
      gvec[((size_t)b * NCH + c) * 64 + lane] = qn;
    } else {
      fvec[((size_t)b * NCH + c) * 64 + lane] = qn;
      if (lane == 0) Lf[b * NCH + c] = Cacc;
    }
  }

  // ---- arrive; the 32nd block of this batch stitches ----
  __threadfence();
  int old = 0;
  if (lane == 0) old = atomicAdd(&counters[b], 1);
  old = __shfl(old, 0);
  if (old != 31) return;
  __threadfence();

  const int C = (len - 1 + CH - 1) / CH;

  float np = (lane < C) ? numpart[b * NCH + lane] : 0.f;
#pragma unroll
  for (int off = 1; off < 64; off <<= 1) np += __shfl_xor(np, off);
  const int tg0 = tag[b * Sn];
  const int tgl = tag[b * Sn + len - 1];
  np += startT[tg0] + emb[tg0] + endT[tgl];

  float den;
  if (C == 0) {  // len == 1
    float v = live ? (startT[jc] + emb[jc] + endT[jc]) : -INFINITY;
    float M = v;
#pragma unroll
    for (int off = 1; off < 64; off <<= 1) M = fmaxf(M, __shfl_xor(M, off));
    float s = __expf(v - M);
#pragma unroll
    for (int off = 1; off < 64; off <<= 1) s += __shfl_xor(s, off);
    den = M + __logf(s);
  } else {
    const float ev = live ? __expf(endT[jc]) : 0.f;
    float d = fvec[((size_t)b * NCH + C - 1) * 64 + lane] * ev;
#pragma unroll
    for (int off = 1; off < 64; off <<= 1) d += __shfl_xor(d, off);
    den = Lf[b * NCH + C - 1] + __logf(d);
    for (int c2 = 1; c2 < C; ++c2) {
      const float g = gvec[((size_t)b * NCH + c2) * 64 + lane];
      const float f = fvec[((size_t)b * NCH + c2 - 1) * 64 + lane];
      float dot = g * f;
      float gs = g;
#pragma unroll
      for (int off = 1; off < 64; off <<= 1) {
        dot += __shfl_xor(dot, off);
        gs += __shfl_xor(gs, off);
      }
      den += Lf[b * NCH + c2 - 1] + __logf(dot) - __logf(gs);
    }
  }
  if (lane == 0) out[b] = den - np;
}

extern "C" void kernel_launch(void* const* d_in, const int* in_sizes, int n_in,
                              void* d_out, int out_size, void* d_ws,
                              size_t ws_size, hipStream_t stream) {
  const float* hidden = (const float*)d_in[0];
  const float* W = (const float*)d_in[1];
  const float* bias = (const float*)d_in[2];
  const float* startT = (const float*)d_in[3];
  const float* endT = (const float*)d_in[4];
  const float* trans = (const float*)d_in[5];
  const int* tag = (const int*)d_in[6];
  const int* mask = (const int*)d_in[7];
  float* out = (float*)d_out;

  // ws layout (16B-aligned offsets)
  char* ws = (char*)d_ws;
  float* em = (float*)ws;                       // 6,553,600 B
  uint32_t* wfrag = (uint32_t*)(ws + 6553600);  //    98,304 B
  int* lenbuf = (int*)(ws + 6651904);           //       256 B
  float* Ee = (float*)(ws + 6652160);           //    10,816 B
  float* EeT = (float*)(ws + 6662976);          //    10,816 B
  float* fvec = (float*)(ws + 6673792);         //   262,144 B
  float* gvec = (float*)(ws + 6935936);         //   262,144 B
  float* Lf = (float*)(ws + 7198080);           //     4,096 B
  float* numpart = (float*)(ws + 7202176);      //     4,096 B
  int* counters = (int*)(ws + 7206272);         //       256 B

  prep_kernel<<<89, 256, 0, stream>>>(W, trans, mask, wfrag, lenbuf, Ee, EeT,
                                      counters);
  emissions_kernel<<<(Bn * Sn) / 64, 256, 0, stream>>>(hidden, wfrag, bias,
                                                       lenbuf, em);
  scan_stitch_kernel<<<Bn * NCH * 2, 64, 0, stream>>>(
      em, startT, endT, trans, Ee, EeT, tag, lenbuf, fvec, gvec, Lf, numpart,
      counters, out);
}

// Round 9
// 87.960 us; speedup vs baseline: 2.1783x; 1.1401x over previous
//
#include <hip/hip_runtime.h>
#include <cstdint>
#include <cstddef>

#define Bn 64
#define Sn 512
#define Hn 768
#define Tn 50
#define CH 32   // scan chunk length (steps)
#define NCH 16  // max chunks per sequence
#define EP 52   // padded row stride for exp(trans) tables
#define BK 64

typedef short short8 __attribute__((ext_vector_type(8)));
typedef float floatx4 __attribute__((ext_vector_type(4)));

__device__ __forceinline__ uint32_t rne_bf16(float x) {
  uint32_t u = __float_as_uint(x);
  return (u + 0x7FFFu + ((u >> 16) & 1u)) >> 16;
}
__device__ __forceinline__ uint32_t pack2(float a, float b) {
  return rne_bf16(a) | (rne_bf16(b) << 16);
}
__device__ __forceinline__ float rdlane(float v, int i) {
  return __uint_as_float(__builtin_amdgcn_readlane(__float_as_uint(v), i));
}

// ------ Kernel 0: prep — lengths + W fragment pack + exp(trans) tables ------
__global__ __launch_bounds__(256) void prep_kernel(
    const float* __restrict__ W, const float* __restrict__ trans,
    const int* __restrict__ mask, uint32_t* __restrict__ wfrag,
    int* __restrict__ lenbuf, float* __restrict__ Ee,
    float* __restrict__ EeT) {
  const int blk = blockIdx.x;
  const int tid = threadIdx.x;
  if (blk < 64) {
    if (tid < 64) {
      int s = 0;
      for (int t = tid; t < Sn; t += 64) s += mask[blk * Sn + t];
#pragma unroll
      for (int off = 1; off < 64; off <<= 1) s += __shfl_xor(s, off);
      if (tid == 0) lenbuf[blk] = s;
    }
    return;
  }
  if (blk == 88) {  // exp(trans) and transpose, padded stride EP
    for (int gid = tid; gid < Tn * Tn; gid += 256) {
      const int r = gid / Tn, cl = gid - r * Tn;
      const float v = __expf(trans[gid]);
      Ee[r * EP + cl] = v;
      EeT[cl * EP + r] = v;
    }
    return;
  }
  const int gid = (blk - 64) * 256 + tid;  // [0, 6144)
  const int f = gid >> 6;                  // 0..95
  const int l = gid & 63;
  const int ks = f >> 2, nt = f & 3;
  const int col = nt * 16 + (l & 15);
  const int k0 = ks * 32 + (l >> 4) * 8;
  float v[8];
#pragma unroll
  for (int j = 0; j < 8; ++j)
    v[j] = (col < Tn) ? W[(size_t)(k0 + j) * Tn + col] : 0.f;
  uint4 d;
  d.x = pack2(v[0], v[1]);
  d.y = pack2(v[2], v[3]);
  d.z = pack2(v[4], v[5]);
  d.w = pack2(v[6], v[7]);
  ((uint4*)wfrag)[gid] = d;
}

// ------ Kernel 1: emissions via MFMA, 2-deep ping-pong prefetch ------
// (256,2): VGPR cap 128 (r7/r8 ran this body at 128, no spill) -> 2
// blocks/CU co-resident -> 2x outstanding HBM loads.
__global__ __launch_bounds__(256, 2) void emissions_kernel(
    const float* __restrict__ hidden, const uint32_t* __restrict__ wfrag,
    const float* __restrict__ bias, const int* __restrict__ lenbuf,
    float* __restrict__ em) {
  const int blk = blockIdx.x;
  const int bb = blk >> 3, cc = blk & 7;
  if (cc * 64 >= lenbuf[bb]) return;  // rows never read by CRF
  const int tid = threadIdx.x;
  const int lane = tid & 63;
  const int w = tid >> 6;
  const int g = lane >> 4;
  const int li = lane & 15;
  const int row0 = blk * 64;
  __shared__ char lds_raw[64 * 128];

  floatx4 acc[4];
#pragma unroll
  for (int nt = 0; nt < 4; ++nt) acc[nt] = (floatx4)0.f;

  const float* hbase = hidden + (size_t)row0 * Hn;
  const short8* wf = (const short8*)wfrag;

#define LOADCH(dst, ch)                                                      \
  _Pragma("unroll") for (int k = 0; k < 4; ++k) dst[k] =                     \
      *(const float4*)(hbase + (size_t)(w * 16 + 4 * k + g) * Hn + (ch)*BK + \
                       li * 4);
#define WRITELDS(src)                                                        \
  _Pragma("unroll") for (int k = 0; k < 4; ++k) {                            \
    const int r = w * 16 + 4 * k + g;                                        \
    const uint32_t b0 = pack2(src[k].x, src[k].y);                           \
    const uint32_t b1 = pack2(src[k].z, src[k].w);                           \
    const int byteoff = r * 128 + ((li * 8) ^ ((r & 7) << 4));               \
    *(uint2*)(lds_raw + byteoff) = make_uint2(b0, b1);                       \
  }
#define COMPUTE(ch)                                                          \
  _Pragma("unroll") for (int ks = 0; ks < 2; ++ks) {                         \
    const int r = w * 16 + li;                                               \
    const int kb = ks * 64 + g * 16;                                         \
    const short8 af =                                                        \
        *(const short8*)(lds_raw + r * 128 + (kb ^ ((r & 7) << 4)));         \
    const int ksg = (ch)*2 + ks;                                             \
    _Pragma("unroll") for (int nt = 0; nt < 4; ++nt) {                       \
      const short8 bf = wf[(ksg * 4 + nt) * 64 + lane];                      \
      acc[nt] =                                                              \
          __builtin_amdgcn_mfma_f32_16x16x32_bf16(af, bf, acc[nt], 0, 0, 0); \
    }                                                                        \
  }

  float4 pfA[4], pfB[4];
  LOADCH(pfA, 0)
  LOADCH(pfB, 1)
#pragma unroll
  for (int chp = 0; chp < Hn / BK / 2; ++chp) {
    const int ch = 2 * chp;
    WRITELDS(pfA)
    if (ch + 2 < Hn / BK) LOADCH(pfA, ch + 2)
    COMPUTE(ch)
    WRITELDS(pfB)
    if (ch + 3 < Hn / BK) LOADCH(pfB, ch + 3)
    COMPUTE(ch + 1)
  }
#undef LOADCH
#undef WRITELDS
#undef COMPUTE

#pragma unroll
  for (int nt = 0; nt < 4; ++nt) {
    const int col = nt * 16 + li;
    if (col < Tn) {
      const float bs = bias[col];
#pragma unroll
      for (int r = 0; r < 4; ++r) {
        const int row = row0 + w * 16 + g * 4 + r;
        em[(size_t)row * Tn + col] = acc[nt][r] + bs;
      }
    }
  }
}

// ------ Kernel 2: chunked scans, 4 same-dir tasks per wave ------
// Blocks 0..255: fwd tasks f = c*64+b, block i owns f = 4i..4i+3 (same c,
// 4 batches). Blocks 256..495: bwd tasks g = (c-1)*64+b, same packing.
// All tasks in a wave share e[50] (depends only on dir); 4 independent
// readlane/FMA chains interleave -> latency hidden by ILP, not TLP.
// Per-task guards are wave-uniform (lengths are per-block scalars).
// No stitch tail here: r8 proved fusing it evicts e[] to scratch.
__global__ __launch_bounds__(64, 1) void scan4_kernel(
    const float* __restrict__ em, const float* __restrict__ startT,
    const float* __restrict__ trans, const float* __restrict__ Ee,
    const float* __restrict__ EeT, const int* __restrict__ tag,
    const int* __restrict__ lenbuf, float* __restrict__ fvec,
    float* __restrict__ gvec, float* __restrict__ Lf,
    float* __restrict__ numpart) {
  const int blk = blockIdx.x;
  const int lane = threadIdx.x;
  const int dir = blk >= 256 ? 1 : 0;
  const int base = (dir ? blk - 256 : blk) * 4;
  const int jc = lane < Tn ? lane : 0;
  const bool live = lane < Tn;

  int bt[4], ct[4], t0t[4], t1t[4], Lt[4];
  int Lmax = 0;
#pragma unroll
  for (int u = 0; u < 4; ++u) {
    const int f = base + u;
    bt[u] = f & 63;
    ct[u] = (f >> 6) + dir;
    const int len = lenbuf[bt[u]];
    t0t[u] = 1 + ct[u] * CH;
    int t1 = t0t[u] + CH;
    if (t1 > len) t1 = len;
    t1t[u] = t1;
    int L = t1 - t0t[u];
    if (L < 0) L = 0;
    Lt[u] = L;
    if (L > Lmax) Lmax = L;
  }
  if (Lmax == 0) return;

  // ---- numerator partials (fwd tasks only); lane = timestep ----
  if (!dir) {
#pragma unroll
    for (int u = 0; u < 4; ++u) {
      if (Lt[u] == 0) continue;
      float npv = 0.f;
      if (lane < Lt[u]) {
        const int t = t0t[u] + lane;
        const int tp = tag[bt[u] * Sn + t - 1], tc = tag[bt[u] * Sn + t];
        npv = trans[tp * Tn + tc] + em[((size_t)bt[u] * Sn + t) * Tn + tc];
      }
#pragma unroll
      for (int off = 1; off < 64; off <<= 1) npv += __shfl_xor(npv, off);
      if (lane == 0) numpart[bt[u] * NCH + ct[u]] = npv;
    }
  }

  // ---- shared E fragment: fwd E[i][jc]=EeT row jc; bwd E[jc][i]=Ee row jc
  const float* ebase = (dir ? Ee : EeT) + jc * EP;
  float e[Tn];
#pragma unroll
  for (int i = 0; i < Tn; ++i) e[i] = ebase[i];

  // ---- per-task state init ----
  float q[4], Cacc[4], eev[4], ld1[4];
#pragma unroll
  for (int u = 0; u < 4; ++u) {
    Cacc[u] = 0.f;
    q[u] = 0.f;
    eev[u] = 0.f;
    ld1[u] = 0.f;
    if (Lt[u] == 0) continue;
    const float* emb = em + (size_t)bt[u] * Sn * Tn;
    if (!dir)
      q[u] = live ? (ct[u] == 0 ? __expf(startT[jc] + emb[jc]) : 1.f) : 0.f;
    else
      q[u] = live ? 1.f : 0.f;
    const int T0 = dir ? (t1t[u] - 1) : t0t[u];
    const int T1 =
        Lt[u] > 1 ? (dir ? t1t[u] - 2 : t0t[u] + 1) : T0;
    const float l0 = emb[(size_t)T0 * Tn + jc];
    ld1[u] = emb[(size_t)T1 * Tn + jc];
    eev[u] = live ? __expf(l0) : 0.f;
  }

  // ---- main scan loop: 4 interleaved chains ----
  for (int k = 0; k < CH; ++k) {
#pragma unroll
    for (int u = 0; u < 4; ++u) {
      if (k >= Lt[u]) continue;  // wave-uniform branch
      const float* emb = em + (size_t)bt[u] * Sn * Tn;
      const float ee_cur = eev[u];
      int kn = k + 2;
      if (kn > Lt[u] - 1) kn = Lt[u] - 1;
      const int tn = dir ? (t1t[u] - 1 - kn) : (t0t[u] + kn);
      const float ldn = emb[(size_t)tn * Tn + jc];
      eev[u] = live ? __expf(ld1[u]) : 0.f;
      ld1[u] = ldn;

      const float x = dir ? ee_cur * q[u] : q[u];
      float s0 = 0.f, s1 = 0.f, s2 = 0.f, s3 = 0.f;
#pragma unroll
      for (int i = 0; i < 48; i += 4) {
        s0 = fmaf(rdlane(x, i + 0), e[i + 0], s0);
        s1 = fmaf(rdlane(x, i + 1), e[i + 1], s1);
        s2 = fmaf(rdlane(x, i + 2), e[i + 2], s2);
        s3 = fmaf(rdlane(x, i + 3), e[i + 3], s3);
      }
      s0 = fmaf(rdlane(x, 48), e[48], s0);
      s1 = fmaf(rdlane(x, 49), e[49], s1);
      const float s = (s0 + s1) + (s2 + s3);
      q[u] = dir ? s : ee_cur * s;
    }
    if ((k & 7) == 7) {  // renorm (bounded < e^60 between renorms)
#pragma unroll
      for (int u = 0; u < 4; ++u) {
        if (k >= Lt[u]) continue;
        float M = q[u];
#pragma unroll
        for (int off = 1; off < 64; off <<= 1) M = fmaxf(M, __shfl_xor(M, off));
        const float r = __builtin_amdgcn_rcpf(M);
        q[u] *= r;
        Cacc[u] -= __logf(r);
      }
    }
  }

  // ---- final renorm + stores ----
#pragma unroll
  for (int u = 0; u < 4; ++u) {
    if (Lt[u] == 0) continue;
    float M = q[u];
#pragma unroll
    for (int off = 1; off < 64; off <<= 1) M = fmaxf(M, __shfl_xor(M, off));
    const float r = __builtin_amdgcn_rcpf(M);
    const float qn = live ? q[u] * r : 0.f;
    Cacc[u] -= __logf(r);
    if (dir) {
      gvec[((size_t)bt[u] * NCH + ct[u]) * 64 + lane] = qn;
    } else {
      fvec[((size_t)bt[u] * NCH + ct[u]) * 64 + lane] = qn;
      if (lane == 0) Lf[bt[u] * NCH + ct[u]] = Cacc[u];
    }
  }
}

// ------ Kernel 3: stitch — rank-1 chain + numerator (r6, unchanged) ------
__global__ __launch_bounds__(64) void stitch_kernel(
    const float* __restrict__ em, const float* __restrict__ startT,
    const float* __restrict__ endT, const int* __restrict__ tag,
    const int* __restrict__ lenbuf, const float* __restrict__ fvec,
    const float* __restrict__ gvec, const float* __restrict__ Lf,
    const float* __restrict__ numpart, float* __restrict__ out) {
  const int b = blockIdx.x;
  const int lane = threadIdx.x;
  const int len = lenbuf[b];
  const int C = (len - 1 + CH - 1) / CH;
  const int jc = lane < Tn ? lane : 0;
  const bool live = lane < Tn;
  const float* emb = em + (size_t)b * Sn * Tn;

  float np = (lane < C) ? numpart[b * NCH + lane] : 0.f;
#pragma unroll
  for (int off = 1; off < 64; off <<= 1) np += __shfl_xor(np, off);
  const int tg0 = tag[b * Sn];
  const int tgl = tag[b * Sn + len - 1];
  np += startT[tg0] + emb[tg0] + endT[tgl];

  float den;
  if (C == 0) {  // len == 1
    float v = live ? (startT[jc] + emb[jc] + endT[jc]) : -INFINITY;
    float M = v;
#pragma unroll
    for (int off = 1; off < 64; off <<= 1) M = fmaxf(M, __shfl_xor(M, off));
    float s = __expf(v - M);
#pragma unroll
    for (int off = 1; off < 64; off <<= 1) s += __shfl_xor(s, off);
    den = M + __logf(s);
  } else {
    const float ev = live ? __expf(endT[jc]) : 0.f;
    float d = fvec[((size_t)b * NCH + C - 1) * 64 + lane] * ev;
#pragma unroll
    for (int off = 1; off < 64; off <<= 1) d += __shfl_xor(d, off);
    den = Lf[b * NCH + C - 1] + __logf(d);
    for (int c2 = 1; c2 < C; ++c2) {
      const float g = gvec[((size_t)b * NCH + c2) * 64 + lane];
      const float f = fvec[((size_t)b * NCH + c2 - 1) * 64 + lane];
      float dot = g * f;
      float gs = g;
#pragma unroll
      for (int off = 1; off < 64; off <<= 1) {
        dot += __shfl_xor(dot, off);
        gs += __shfl_xor(gs, off);
      }
      den += Lf[b * NCH + c2 - 1] + __logf(dot) - __logf(gs);
    }
  }
  if (lane == 0) out[b] = den - np;
}

extern "C" void kernel_launch(void* const* d_in, const int* in_sizes, int n_in,
                              void* d_out, int out_size, void* d_ws,
                              size_t ws_size, hipStream_t stream) {
  const float* hidden = (const float*)d_in[0];
  const float* W = (const float*)d_in[1];
  const float* bias = (const float*)d_in[2];
  const float* startT = (const float*)d_in[3];
  const float* endT = (const float*)d_in[4];
  const float* trans = (const float*)d_in[5];
  const int* tag = (const int*)d_in[6];
  const int* mask = (const int*)d_in[7];
  float* out = (float*)d_out;

  // ws layout (16B-aligned offsets)
  char* ws = (char*)d_ws;
  float* em = (float*)ws;                       // 6,553,600 B
  uint32_t* wfrag = (uint32_t*)(ws + 6553600);  //    98,304 B
  int* lenbuf = (int*)(ws + 6651904);           //       256 B
  float* Ee = (float*)(ws + 6652160);           //    10,816 B
  float* EeT = (float*)(ws + 6662976);          //    10,816 B
  float* fvec = (float*)(ws + 6673792);         //   262,144 B
  float* gvec = (float*)(ws + 6935936);         //   262,144 B
  float* Lf = (float*)(ws + 7198080);           //     4,096 B
  float* numpart = (float*)(ws + 7202176);      //     4,096 B

  prep_kernel<<<89, 256, 0, stream>>>(W, trans, mask, wfrag, lenbuf, Ee, EeT);
  emissions_kernel<<<(Bn * Sn) / 64, 256, 0, stream>>>(hidden, wfrag, bias,
                                                       lenbuf, em);
  scan4_kernel<<<496, 64, 0, stream>>>(em, startT, trans, Ee, EeT, tag, lenbuf,
                                       fvec, gvec, Lf, numpart);
  stitch_kernel<<<Bn, 64, 0, stream>>>(em, startT, endT, tag, lenbuf, fvec,
                                       gvec, Lf, numpart, out);
}

// Round 10
// 61.721 us; speedup vs baseline: 3.1043x; 1.4251x over previous
//
#include <hip/hip_runtime.h>
#include <cstdint>
#include <cstddef>

#define Bn 64
#define Sn 512
#define Hn 768
#define Tn 50
#define CH 32   // scan chunk length (steps)
#define NCH 16  // max chunks per sequence = ceil((Sn-1)/CH)
#define EP 52   // padded row stride for exp(trans) tables (208 B, 16B-aligned)

typedef short short8 __attribute__((ext_vector_type(8)));
typedef float floatx4 __attribute__((ext_vector_type(4)));

__device__ __forceinline__ uint32_t rne_bf16(float x) {
  uint32_t u = __float_as_uint(x);
  return (u + 0x7FFFu + ((u >> 16) & 1u)) >> 16;
}
__device__ __forceinline__ uint32_t pack2(float a, float b) {
  return rne_bf16(a) | (rne_bf16(b) << 16);
}
__device__ __forceinline__ float rdlane(float v, int i) {
  return __uint_as_float(__builtin_amdgcn_readlane(__float_as_uint(v), i));
}

// ------ Kernel 0: prep — lengths + W fragment pack + exp(trans) tables ------
__global__ __launch_bounds__(256) void prep_kernel(
    const float* __restrict__ W, const float* __restrict__ trans,
    const int* __restrict__ mask, uint32_t* __restrict__ wfrag,
    int* __restrict__ lenbuf, float* __restrict__ Ee,
    float* __restrict__ EeT) {
  const int blk = blockIdx.x;
  const int tid = threadIdx.x;
  if (blk < 64) {
    if (tid < 64) {
      int s = 0;
      for (int t = tid; t < Sn; t += 64) s += mask[blk * Sn + t];
#pragma unroll
      for (int off = 1; off < 64; off <<= 1) s += __shfl_xor(s, off);
      if (tid == 0) lenbuf[blk] = s;
    }
    return;
  }
  if (blk == 88) {  // exp(trans) and transpose, padded stride EP
    for (int gid = tid; gid < Tn * Tn; gid += 256) {
      const int r = gid / Tn, cl = gid - r * Tn;
      const float v = __expf(trans[gid]);
      Ee[r * EP + cl] = v;
      EeT[cl * EP + r] = v;
    }
    return;
  }
  const int gid = (blk - 64) * 256 + tid;  // [0, 6144)
  const int f = gid >> 6;                  // 0..95
  const int l = gid & 63;
  const int ks = f >> 2, nt = f & 3;
  const int col = nt * 16 + (l & 15);
  const int k0 = ks * 32 + (l >> 4) * 8;
  float v[8];
#pragma unroll
  for (int j = 0; j < 8; ++j)
    v[j] = (col < Tn) ? W[(size_t)(k0 + j) * Tn + col] : 0.f;
  uint4 d;
  d.x = pack2(v[0], v[1]);
  d.y = pack2(v[2], v[3]);
  d.z = pack2(v[4], v[5]);
  d.w = pack2(v[6], v[7]);
  ((uint4*)wfrag)[gid] = d;
}

// ------ Kernel 1: emissions via MFMA, 2-deep ping-pong prefetch ------
// (256,2): VGPR cap 128 — measured in r8 at ~16-18 us (vs ~30 at (256,1)):
// 2 blocks/CU co-resident doubles outstanding HBM loads. Body identical to
// r6 (no spill at 128 per r7's fused VGPR_Count).
#define BK 64
__global__ __launch_bounds__(256, 2) void emissions_kernel(
    const float* __restrict__ hidden, const uint32_t* __restrict__ wfrag,
    const float* __restrict__ bias, const int* __restrict__ lenbuf,
    float* __restrict__ em) {
  const int blk = blockIdx.x;
  const int bb = blk >> 3, cc = blk & 7;
  if (cc * 64 >= lenbuf[bb]) return;  // rows never read by CRF
  const int tid = threadIdx.x;
  const int lane = tid & 63;
  const int w = tid >> 6;
  const int g = lane >> 4;
  const int li = lane & 15;
  const int row0 = blk * 64;
  __shared__ char lds_raw[64 * 128];

  floatx4 acc[4];
#pragma unroll
  for (int nt = 0; nt < 4; ++nt) acc[nt] = (floatx4)0.f;

  const float* hbase = hidden + (size_t)row0 * Hn;
  const short8* wf = (const short8*)wfrag;

#define LOADCH(dst, ch)                                                      \
  _Pragma("unroll") for (int k = 0; k < 4; ++k) dst[k] =                     \
      *(const float4*)(hbase + (size_t)(w * 16 + 4 * k + g) * Hn + (ch)*BK + \
                       li * 4);
#define WRITELDS(src)                                                        \
  _Pragma("unroll") for (int k = 0; k < 4; ++k) {                            \
    const int r = w * 16 + 4 * k + g;                                        \
    const uint32_t b0 = pack2(src[k].x, src[k].y);                           \
    const uint32_t b1 = pack2(src[k].z, src[k].w);                           \
    const int byteoff = r * 128 + ((li * 8) ^ ((r & 7) << 4));               \
    *(uint2*)(lds_raw + byteoff) = make_uint2(b0, b1);                       \
  }
#define COMPUTE(ch)                                                          \
  _Pragma("unroll") for (int ks = 0; ks < 2; ++ks) {                         \
    const int r = w * 16 + li;                                               \
    const int kb = ks * 64 + g * 16;                                         \
    const short8 af =                                                        \
        *(const short8*)(lds_raw + r * 128 + (kb ^ ((r & 7) << 4)));         \
    const int ksg = (ch)*2 + ks;                                             \
    _Pragma("unroll") for (int nt = 0; nt < 4; ++nt) {                       \
      const short8 bf = wf[(ksg * 4 + nt) * 64 + lane];                      \
      acc[nt] =                                                              \
          __builtin_amdgcn_mfma_f32_16x16x32_bf16(af, bf, acc[nt], 0, 0, 0); \
    }                                                                        \
  }

  float4 pfA[4], pfB[4];
  LOADCH(pfA, 0)
  LOADCH(pfB, 1)
#pragma unroll
  for (int chp = 0; chp < Hn / BK / 2; ++chp) {
    const int ch = 2 * chp;
    WRITELDS(pfA)
    if (ch + 2 < Hn / BK) LOADCH(pfA, ch + 2)
    COMPUTE(ch)
    WRITELDS(pfB)
    if (ch + 3 < Hn / BK) LOADCH(pfB, ch + 3)
    COMPUTE(ch + 1)
  }
#undef LOADCH
#undef WRITELDS
#undef COMPUTE

#pragma unroll
  for (int nt = 0; nt < 4; ++nt) {
    const int col = nt * 16 + li;
    if (col < Tn) {
      const float bs = bias[col];
#pragma unroll
      for (int r = 0; r < 4; ++r) {
        const int row = row0 + w * 16 + g * 4 + r;
        em[(size_t)row * Tn + col] = acc[nt][r] + bs;
      }
    }
  }
}

// ------ Kernel 2: chunked scans (f forward / g backward) — r6 verbatim ------
// __launch_bounds__(64, 1): VGPR cap 512 so e[50] stays in registers.
// Single task per wave: the ONLY shape proven not to spill (r3/r8/r9).
__global__ __launch_bounds__(64, 1) void scan_kernel(
    const float* __restrict__ em, const float* __restrict__ startT,
    const float* __restrict__ trans, const float* __restrict__ Ee,
    const float* __restrict__ EeT, const int* __restrict__ tag,
    const int* __restrict__ lenbuf, float* __restrict__ fvec,
    float* __restrict__ gvec, float* __restrict__ Lf,
    float* __restrict__ numpart) {
  const int blk = blockIdx.x;
  const int b = blk >> 5;
  const int c = (blk >> 1) & (NCH - 1);
  const int dir = blk & 1;  // 0 = forward (f), 1 = backward (g)
  const int len = lenbuf[b];
  const int t0 = 1 + c * CH;
  if (t0 >= len) return;
  if (dir && c == 0) return;
  const int t1 = (t0 + CH < len) ? t0 + CH : len;
  const int L = t1 - t0;
  const int lane = threadIdx.x;
  const int jc = lane < Tn ? lane : 0;
  const bool live = lane < Tn;
  const float* emb = em + (size_t)b * Sn * Tn;

  if (!dir) {  // chunk numerator partial; lane = timestep
    float npv = 0.f;
    if (lane < L) {
      const int t = t0 + lane;
      const int tp = tag[b * Sn + t - 1], tc = tag[b * Sn + t];
      npv = trans[tp * Tn + tc] + emb[(size_t)t * Tn + tc];
    }
#pragma unroll
    for (int off = 1; off < 64; off <<= 1) npv += __shfl_xor(npv, off);
    if (lane == 0) numpart[b * NCH + c] = npv;
  }

  // e[i]: f needs E[i][jc] = EeT row jc; g needs E[jc][i] = Ee row jc.
  const float* ebase = (dir ? Ee : EeT) + jc * EP;
  float e[Tn];
#pragma unroll
  for (int i = 0; i < Tn; ++i) e[i] = ebase[i];

  float Cacc = 0.f;
  float q;
  if (!dir)
    q = live ? (c == 0 ? __expf(startT[jc] + emb[jc]) : 1.f) : 0.f;
  else
    q = live ? 1.f : 0.f;

#define T_OF(k) (dir ? (t1 - 1 - (k)) : (t0 + (k)))
  float ld1 = emb[(size_t)T_OF(0) * Tn + jc];
  const float ld2 = emb[(size_t)T_OF(L > 1 ? 1 : 0) * Tn + jc];
  float ee = live ? __expf(ld1) : 0.f;
  ld1 = ld2;

  for (int k = 0; k < L; ++k) {
    const float ee_cur = ee;
    const int kn = (k + 2 < L) ? k + 2 : L - 1;
    const float ldn = emb[(size_t)T_OF(kn) * Tn + jc];
    ee = live ? __expf(ld1) : 0.f;
    ld1 = ldn;

    const float x = dir ? ee_cur * q : q;  // g pre-multiplies by D_t
    float s0 = 0.f, s1 = 0.f, s2 = 0.f, s3 = 0.f;
#pragma unroll
    for (int i = 0; i < 48; i += 4) {
      s0 = fmaf(rdlane(x, i + 0), e[i + 0], s0);
      s1 = fmaf(rdlane(x, i + 1), e[i + 1], s1);
      s2 = fmaf(rdlane(x, i + 2), e[i + 2], s2);
      s3 = fmaf(rdlane(x, i + 3), e[i + 3], s3);
    }
    s0 = fmaf(rdlane(x, 48), e[48], s0);
    s1 = fmaf(rdlane(x, 49), e[49], s1);
    const float s = (s0 + s1) + (s2 + s3);
    q = dir ? s : ee_cur * s;  // f post-multiplies by D_t

    if ((k & 7) == 7) {
      float M = q;
#pragma unroll
      for (int off = 1; off < 64; off <<= 1) M = fmaxf(M, __shfl_xor(M, off));
      const float r = __builtin_amdgcn_rcpf(M);
      q *= r;
      Cacc -= __logf(r);
    }
  }
#undef T_OF

  float M = q;
#pragma unroll
  for (int off = 1; off < 64; off <<= 1) M = fmaxf(M, __shfl_xor(M, off));
  const float r = __builtin_amdgcn_rcpf(M);
  const float qn = live ? q * r : 0.f;
  Cacc -= __logf(r);
  if (dir) {
    gvec[((size_t)b * NCH + c) * 64 + lane] = qn;
  } else {
    fvec[((size_t)b * NCH + c) * 64 + lane] = qn;
    if (lane == 0) Lf[b * NCH + c] = Cacc;
  }
}

// ------ Kernel 3: stitch — rank-1 chain + numerator (r6 verbatim) ------
__global__ __launch_bounds__(64) void stitch_kernel(
    const float* __restrict__ em, const float* __restrict__ startT,
    const float* __restrict__ endT, const int* __restrict__ tag,
    const int* __restrict__ lenbuf, const float* __restrict__ fvec,
    const float* __restrict__ gvec, const float* __restrict__ Lf,
    const float* __restrict__ numpart, float* __restrict__ out) {
  const int b = blockIdx.x;
  const int lane = threadIdx.x;
  const int len = lenbuf[b];
  const int C = (len - 1 + CH - 1) / CH;
  const int jc = lane < Tn ? lane : 0;
  const bool live = lane < Tn;
  const float* emb = em + (size_t)b * Sn * Tn;

  float np = (lane < C) ? numpart[b * NCH + lane] : 0.f;
#pragma unroll
  for (int off = 1; off < 64; off <<= 1) np += __shfl_xor(np, off);
  const int tg0 = tag[b * Sn];
  const int tgl = tag[b * Sn + len - 1];
  np += startT[tg0] + emb[tg0] + endT[tgl];

  float den;
  if (C == 0) {  // len == 1
    float v = live ? (startT[jc] + emb[jc] + endT[jc]) : -INFINITY;
    float M = v;
#pragma unroll
    for (int off = 1; off < 64; off <<= 1) M = fmaxf(M, __shfl_xor(M, off));
    float s = __expf(v - M);
#pragma unroll
    for (int off = 1; off < 64; off <<= 1) s += __shfl_xor(s, off);
    den = M + __logf(s);
  } else {
    const float ev = live ? __expf(endT[jc]) : 0.f;
    float d = fvec[((size_t)b * NCH + C - 1) * 64 + lane] * ev;
#pragma unroll
    for (int off = 1; off < 64; off <<= 1) d += __shfl_xor(d, off);
    den = Lf[b * NCH + C - 1] + __logf(d);
    for (int c2 = 1; c2 < C; ++c2) {
      const float g = gvec[((size_t)b * NCH + c2) * 64 + lane];
      const float f = fvec[((size_t)b * NCH + c2 - 1) * 64 + lane];
      float dot = g * f;
      float gs = g;
#pragma unroll
      for (int off = 1; off < 64; off <<= 1) {
        dot += __shfl_xor(dot, off);
        gs += __shfl_xor(gs, off);
      }
      den += Lf[b * NCH + c2 - 1] + __logf(dot) - __logf(gs);
    }
  }
  if (lane == 0) out[b] = den - np;
}

extern "C" void kernel_launch(void* const* d_in, const int* in_sizes, int n_in,
                              void* d_out, int out_size, void* d_ws,
                              size_t ws_size, hipStream_t stream) {
  const float* hidden = (const float*)d_in[0];
  const float* W = (const float*)d_in[1];
  const float* bias = (const float*)d_in[2];
  const float* startT = (const float*)d_in[3];
  const float* endT = (const float*)d_in[4];
  const float* trans = (const float*)d_in[5];
  const int* tag = (const int*)d_in[6];
  const int* mask = (const int*)d_in[7];
  float* out = (float*)d_out;

  // ws layout (16B-aligned offsets)
  char* ws = (char*)d_ws;
  float* em = (float*)ws;                       // 6,553,600 B
  uint32_t* wfrag = (uint32_t*)(ws + 6553600);  //    98,304 B
  int* lenbuf = (int*)(ws + 6651904);           //       256 B
  float* Ee = (float*)(ws + 6652160);           //    10,816 B
  float* EeT = (float*)(ws + 6662976);          //    10,816 B
  float* fvec = (float*)(ws + 6673792);         //   262,144 B
  float* gvec = (float*)(ws + 6935936);         //   262,144 B
  float* Lf = (float*)(ws + 7198080);           //     4,096 B
  float* numpart = (float*)(ws + 7202176);      //     4,096 B

  prep_kernel<<<89, 256, 0, stream>>>(W, trans, mask, wfrag, lenbuf, Ee, EeT);
  emissions_kernel<<<(Bn * Sn) / 64, 256, 0, stream>>>(hidden, wfrag, bias,
                                                       lenbuf, em);
  scan_kernel<<<Bn * NCH * 2, 64, 0, stream>>>(em, startT, trans, Ee, EeT, tag,
                                               lenbuf, fvec, gvec, Lf, numpart);
  stitch_kernel<<<Bn, 64, 0, stream>>>(em, startT, endT, tag, lenbuf, fvec,
                                       gvec, Lf, numpart, out);
}

// Round 11
// 61.244 us; speedup vs baseline: 3.1285x; 1.0078x over previous
//
#include <hip/hip_runtime.h>
#include <cstdint>
#include <cstddef>

#define Bn 64
#define Sn 512
#define Hn 768
#define Tn 50
#define CH 16   // scan chunk length (steps)
#define NCH 32  // max chunks per sequence = ceil((Sn-1)/CH)

typedef short short8 __attribute__((ext_vector_type(8)));
typedef float floatx4 __attribute__((ext_vector_type(4)));

__device__ __forceinline__ uint32_t rne_bf16(float x) {
  uint32_t u = __float_as_uint(x);
  return (u + 0x7FFFu + ((u >> 16) & 1u)) >> 16;
}
__device__ __forceinline__ uint32_t pack2(float a, float b) {
  return rne_bf16(a) | (rne_bf16(b) << 16);
}
__device__ __forceinline__ float rdlane(float v, int i) {
  return __uint_as_float(__builtin_amdgcn_readlane(__float_as_uint(v), i));
}

// ------ Kernel 0: prep — lengths + W fragment pack + packed E tables ------
// Packed layout: EfwdP[i*64+j] = exp(trans[i][j]); EbwdP[i*64+j] =
// exp(trans[j][i]). Scan's e[i] load (fixed i, lanes j) is then ONE
// coalesced 256B line instead of a 50-line stride-208B gather.
__global__ __launch_bounds__(256) void prep_kernel(
    const float* __restrict__ W, const float* __restrict__ trans,
    const int* __restrict__ mask, uint32_t* __restrict__ wfrag,
    int* __restrict__ lenbuf, float* __restrict__ EfwdP,
    float* __restrict__ EbwdP) {
  const int blk = blockIdx.x;
  const int tid = threadIdx.x;
  if (blk < 64) {
    if (tid < 64) {
      int s = 0;
      for (int t = tid; t < Sn; t += 64) s += mask[blk * Sn + t];
#pragma unroll
      for (int off = 1; off < 64; off <<= 1) s += __shfl_xor(s, off);
      if (tid == 0) lenbuf[blk] = s;
    }
    return;
  }
  if (blk == 88) {  // packed exp(trans) tables
    for (int gid = tid; gid < Tn * 64; gid += 256) {
      const int i = gid >> 6, j = gid & 63;
      EfwdP[gid] = (j < Tn) ? __expf(trans[i * Tn + j]) : 0.f;
      EbwdP[gid] = (j < Tn) ? __expf(trans[j * Tn + i]) : 0.f;
    }
    return;
  }
  const int gid = (blk - 64) * 256 + tid;  // [0, 6144)
  const int f = gid >> 6;                  // 0..95
  const int l = gid & 63;
  const int ks = f >> 2, nt = f & 3;
  const int col = nt * 16 + (l & 15);
  const int k0 = ks * 32 + (l >> 4) * 8;
  float v[8];
#pragma unroll
  for (int j = 0; j < 8; ++j)
    v[j] = (col < Tn) ? W[(size_t)(k0 + j) * Tn + col] : 0.f;
  uint4 d;
  d.x = pack2(v[0], v[1]);
  d.y = pack2(v[2], v[3]);
  d.z = pack2(v[4], v[5]);
  d.w = pack2(v[6], v[7]);
  ((uint4*)wfrag)[gid] = d;
}

// ------ Kernel 1: emissions via MFMA (r6 verbatim, (256,1)) ------
// r10 A/B: (256,2) costs +8.5 us (cap-128 regalloc hurts the ping-pong).
#define BK 64
__global__ __launch_bounds__(256, 1) void emissions_kernel(
    const float* __restrict__ hidden, const uint32_t* __restrict__ wfrag,
    const float* __restrict__ bias, const int* __restrict__ lenbuf,
    float* __restrict__ em) {
  const int blk = blockIdx.x;
  const int bb = blk >> 3, cc = blk & 7;
  if (cc * 64 >= lenbuf[bb]) return;  // rows never read by CRF
  const int tid = threadIdx.x;
  const int lane = tid & 63;
  const int w = tid >> 6;
  const int g = lane >> 4;
  const int li = lane & 15;
  const int row0 = blk * 64;
  __shared__ char lds_raw[64 * 128];

  floatx4 acc[4];
#pragma unroll
  for (int nt = 0; nt < 4; ++nt) acc[nt] = (floatx4)0.f;

  const float* hbase = hidden + (size_t)row0 * Hn;
  const short8* wf = (const short8*)wfrag;

#define LOADCH(dst, ch)                                                      \
  _Pragma("unroll") for (int k = 0; k < 4; ++k) dst[k] =                     \
      *(const float4*)(hbase + (size_t)(w * 16 + 4 * k + g) * Hn + (ch)*BK + \
                       li * 4);
#define WRITELDS(src)                                                        \
  _Pragma("unroll") for (int k = 0; k < 4; ++k) {                            \
    const int r = w * 16 + 4 * k + g;                                        \
    const uint32_t b0 = pack2(src[k].x, src[k].y);                           \
    const uint32_t b1 = pack2(src[k].z, src[k].w);                           \
    const int byteoff = r * 128 + ((li * 8) ^ ((r & 7) << 4));               \
    *(uint2*)(lds_raw + byteoff) = make_uint2(b0, b1);                       \
  }
#define COMPUTE(ch)                                                          \
  _Pragma("unroll") for (int ks = 0; ks < 2; ++ks) {                         \
    const int r = w * 16 + li;                                               \
    const int kb = ks * 64 + g * 16;                                         \
    const short8 af =                                                        \
        *(const short8*)(lds_raw + r * 128 + (kb ^ ((r & 7) << 4)));         \
    const int ksg = (ch)*2 + ks;                                             \
    _Pragma("unroll") for (int nt = 0; nt < 4; ++nt) {                       \
      const short8 bf = wf[(ksg * 4 + nt) * 64 + lane];                      \
      acc[nt] =                                                              \
          __builtin_amdgcn_mfma_f32_16x16x32_bf16(af, bf, acc[nt], 0, 0, 0); \
    }                                                                        \
  }

  float4 pfA[4], pfB[4];
  LOADCH(pfA, 0)
  LOADCH(pfB, 1)
#pragma unroll
  for (int chp = 0; chp < Hn / BK / 2; ++chp) {
    const int ch = 2 * chp;
    WRITELDS(pfA)
    if (ch + 2 < Hn / BK) LOADCH(pfA, ch + 2)
    COMPUTE(ch)
    WRITELDS(pfB)
    if (ch + 3 < Hn / BK) LOADCH(pfB, ch + 3)
    COMPUTE(ch + 1)
  }
#undef LOADCH
#undef WRITELDS
#undef COMPUTE

#pragma unroll
  for (int nt = 0; nt < 4; ++nt) {
    const int col = nt * 16 + li;
    if (col < Tn) {
      const float bs = bias[col];
#pragma unroll
      for (int r = 0; r < 4; ++r) {
        const int row = row0 + w * 16 + g * 4 + r;
        em[(size_t)row * Tn + col] = acc[nt][r] + bs;
      }
    }
  }
}

// ------ Kernel 2: chunked scans (CH=16), packed coalesced e-loads ------
// Single task per wave (the only non-spilling shape, r3/r8/r9).
// __launch_bounds__(64,1): VGPR cap 512 so e[50] stays in registers.
__global__ __launch_bounds__(64, 1) void scan_kernel(
    const float* __restrict__ em, const float* __restrict__ startT,
    const float* __restrict__ trans, const float* __restrict__ EfwdP,
    const float* __restrict__ EbwdP, const int* __restrict__ tag,
    const int* __restrict__ lenbuf, float* __restrict__ fvec,
    float* __restrict__ gvec, float* __restrict__ Lf,
    float* __restrict__ numpart) {
  const int blk = blockIdx.x;
  const int b = blk >> 6;               // NCH*2 = 64 tasks per batch
  const int c = (blk >> 1) & (NCH - 1);
  const int dir = blk & 1;  // 0 = forward (f), 1 = backward (g)
  const int len = lenbuf[b];
  const int t0 = 1 + c * CH;
  if (t0 >= len) return;
  if (dir && c == 0) return;
  const int t1 = (t0 + CH < len) ? t0 + CH : len;
  const int L = t1 - t0;
  const int lane = threadIdx.x;
  const int jc = lane < Tn ? lane : 0;
  const bool live = lane < Tn;
  const float* emb = em + (size_t)b * Sn * Tn;

  if (!dir) {  // chunk numerator partial; lane = timestep (L <= 16)
    float npv = 0.f;
    if (lane < L) {
      const int t = t0 + lane;
      const int tp = tag[b * Sn + t - 1], tc = tag[b * Sn + t];
      npv = trans[tp * Tn + tc] + emb[(size_t)t * Tn + tc];
    }
#pragma unroll
    for (int off = 1; off < 64; off <<= 1) npv += __shfl_xor(npv, off);
    if (lane == 0) numpart[b * NCH + c] = npv;
  }

  // e[i]: coalesced — fixed i, lanes jc read consecutive floats.
  const float* ebase = dir ? EbwdP : EfwdP;
  float e[Tn];
#pragma unroll
  for (int i = 0; i < Tn; ++i) e[i] = ebase[i * 64 + jc];

  float Cacc = 0.f;
  float q;
  if (!dir)
    q = live ? (c == 0 ? __expf(startT[jc] + emb[jc]) : 1.f) : 0.f;
  else
    q = live ? 1.f : 0.f;

#define T_OF(k) (dir ? (t1 - 1 - (k)) : (t0 + (k)))
  float ld1 = emb[(size_t)T_OF(0) * Tn + jc];
  const float ld2 = emb[(size_t)T_OF(L > 1 ? 1 : 0) * Tn + jc];
  float ee = live ? __expf(ld1) : 0.f;
  ld1 = ld2;

  for (int k = 0; k < L; ++k) {
    const float ee_cur = ee;
    const int kn = (k + 2 < L) ? k + 2 : L - 1;
    const float ldn = emb[(size_t)T_OF(kn) * Tn + jc];
    ee = live ? __expf(ld1) : 0.f;
    ld1 = ldn;

    const float x = dir ? ee_cur * q : q;  // g pre-multiplies by D_t
    float s0 = 0.f, s1 = 0.f, s2 = 0.f, s3 = 0.f;
#pragma unroll
    for (int i = 0; i < 48; i += 4) {
      s0 = fmaf(rdlane(x, i + 0), e[i + 0], s0);
      s1 = fmaf(rdlane(x, i + 1), e[i + 1], s1);
      s2 = fmaf(rdlane(x, i + 2), e[i + 2], s2);
      s3 = fmaf(rdlane(x, i + 3), e[i + 3], s3);
    }
    s0 = fmaf(rdlane(x, 48), e[48], s0);
    s1 = fmaf(rdlane(x, 49), e[49], s1);
    const float s = (s0 + s1) + (s2 + s3);
    q = dir ? s : ee_cur * s;  // f post-multiplies by D_t

    if ((k & 7) == 7) {
      float M = q;
#pragma unroll
      for (int off = 1; off < 64; off <<= 1) M = fmaxf(M, __shfl_xor(M, off));
      const float r = __builtin_amdgcn_rcpf(M);
      q *= r;
      Cacc -= __logf(r);
    }
  }
#undef T_OF

  float M = q;
#pragma unroll
  for (int off = 1; off < 64; off <<= 1) M = fmaxf(M, __shfl_xor(M, off));
  const float r = __builtin_amdgcn_rcpf(M);
  const float qn = live ? q * r : 0.f;
  Cacc -= __logf(r);
  if (dir) {
    gvec[((size_t)b * NCH + c) * 64 + lane] = qn;
  } else {
    fvec[((size_t)b * NCH + c) * 64 + lane] = qn;
    if (lane == 0) Lf[b * NCH + c] = Cacc;
  }
}

// ------ Kernel 3: stitch — rank-1 chain + numerator (code unchanged; C<=32) --
__global__ __launch_bounds__(64) void stitch_kernel(
    const float* __restrict__ em, const float* __restrict__ startT,
    const float* __restrict__ endT, const int* __restrict__ tag,
    const int* __restrict__ lenbuf, const float* __restrict__ fvec,
    const float* __restrict__ gvec, const float* __restrict__ Lf,
    const float* __restrict__ numpart, float* __restrict__ out) {
  const int b = blockIdx.x;
  const int lane = threadIdx.x;
  const int len = lenbuf[b];
  const int C = (len - 1 + CH - 1) / CH;
  const int jc = lane < Tn ? lane : 0;
  const bool live = lane < Tn;
  const float* emb = em + (size_t)b * Sn * Tn;

  float np = (lane < C) ? numpart[b * NCH + lane] : 0.f;
#pragma unroll
  for (int off = 1; off < 64; off <<= 1) np += __shfl_xor(np, off);
  const int tg0 = tag[b * Sn];
  const int tgl = tag[b * Sn + len - 1];
  np += startT[tg0] + emb[tg0] + endT[tgl];

  float den;
  if (C == 0) {  // len == 1
    float v = live ? (startT[jc] + emb[jc] + endT[jc]) : -INFINITY;
    float M = v;
#pragma unroll
    for (int off = 1; off < 64; off <<= 1) M = fmaxf(M, __shfl_xor(M, off));
    float s = __expf(v - M);
#pragma unroll
    for (int off = 1; off < 64; off <<= 1) s += __shfl_xor(s, off);
    den = M + __logf(s);
  } else {
    const float ev = live ? __expf(endT[jc]) : 0.f;
    float d = fvec[((size_t)b * NCH + C - 1) * 64 + lane] * ev;
#pragma unroll
    for (int off = 1; off < 64; off <<= 1) d += __shfl_xor(d, off);
    den = Lf[b * NCH + C - 1] + __logf(d);
    for (int c2 = 1; c2 < C; ++c2) {
      const float g = gvec[((size_t)b * NCH + c2) * 64 + lane];
      const float f = fvec[((size_t)b * NCH + c2 - 1) * 64 + lane];
      float dot = g * f;
      float gs = g;
#pragma unroll
      for (int off = 1; off < 64; off <<= 1) {
        dot += __shfl_xor(dot, off);
        gs += __shfl_xor(gs, off);
      }
      den += Lf[b * NCH + c2 - 1] + __logf(dot) - __logf(gs);
    }
  }
  if (lane == 0) out[b] = den - np;
}

extern "C" void kernel_launch(void* const* d_in, const int* in_sizes, int n_in,
                              void* d_out, int out_size, void* d_ws,
                              size_t ws_size, hipStream_t stream) {
  const float* hidden = (const float*)d_in[0];
  const float* W = (const float*)d_in[1];
  const float* bias = (const float*)d_in[2];
  const float* startT = (const float*)d_in[3];
  const float* endT = (const float*)d_in[4];
  const float* trans = (const float*)d_in[5];
  const int* tag = (const int*)d_in[6];
  const int* mask = (const int*)d_in[7];
  float* out = (float*)d_out;

  // ws layout (16B-aligned offsets)
  char* ws = (char*)d_ws;
  float* em = (float*)ws;                       // 6,553,600 B
  uint32_t* wfrag = (uint32_t*)(ws + 6553600);  //    98,304 B
  int* lenbuf = (int*)(ws + 6651904);           //       256 B
  float* EfwdP = (float*)(ws + 6652160);        //    12,800 B
  float* EbwdP = (float*)(ws + 6664960);        //    12,800 B
  float* fvec = (float*)(ws + 6677760);         //   524,288 B
  float* gvec = (float*)(ws + 7202048);         //   524,288 B
  float* Lf = (float*)(ws + 7726336);           //     8,192 B
  float* numpart = (float*)(ws + 7734528);      //     8,192 B

  prep_kernel<<<89, 256, 0, stream>>>(W, trans, mask, wfrag, lenbuf, EfwdP,
                                      EbwdP);
  emissions_kernel<<<(Bn * Sn) / 64, 256, 0, stream>>>(hidden, wfrag, bias,
                                                       lenbuf, em);
  scan_kernel<<<Bn * NCH * 2, 64, 0, stream>>>(em, startT, trans, EfwdP, EbwdP,
                                               tag, lenbuf, fvec, gvec, Lf,
                                               numpart);
  stitch_kernel<<<Bn, 64, 0, stream>>>(em, startT, endT, tag, lenbuf, fvec,
                                       gvec, Lf, numpart, out);
}